// Round 1
// baseline (436.746 us; speedup 1.0000x reference)
//
#include <hip/hip_runtime.h>

#define Bn 2
#define Nn 384
#define Dn 256
#define Rn 128
#define Sn 64
#define BNn (Bn*Nn)

static __device__ __forceinline__ float fast_sigmoid(float x) {
    return __builtin_amdgcn_rcpf(1.0f + __expf(-x));
}

static __device__ __forceinline__ float f4c(const float4& v, int c) {
    return c == 0 ? v.x : c == 1 ? v.y : c == 2 ? v.z : v.w;
}

// ---------------- K0: zero the stats accumulator area ----------------
__global__ void zero_stats(float* __restrict__ stats) {
    if (threadIdx.x < 8) stats[threadIdx.x] = 0.0f;
}

// ---------------- K1: projections q=t@Qs, k=t@Ks, qd=t@Qd, kd=t@Kd ----------------
// grid 768 blocks (one per row), 384 threads (wave-uniform branch per W)
__global__ void proj_kernel(const float* __restrict__ t,
                            const float* __restrict__ Qd, const float* __restrict__ Kd,
                            const float* __restrict__ Qs, const float* __restrict__ Ks,
                            float* __restrict__ q, float* __restrict__ k,
                            float* __restrict__ qdp, float* __restrict__ kdp) {
    __shared__ float trow[Dn];
    const int row = blockIdx.x;
    const int tid = threadIdx.x;
    if (tid < Dn) trow[tid] = t[(size_t)row * Dn + tid];
    __syncthreads();
    const float* W;
    float* o;
    int ncol, col;
    if (tid < 64)       { W = Qs; o = q;   ncol = 64;  col = tid; }
    else if (tid < 128) { W = Ks; o = k;   ncol = 64;  col = tid - 64; }
    else if (tid < 256) { W = Qd; o = qdp; ncol = 128; col = tid - 128; }
    else                { W = Kd; o = kdp; ncol = 128; col = tid - 256; }
    float acc[8];
#pragma unroll
    for (int u = 0; u < 8; ++u) acc[u] = 0.0f;
    for (int kk = 0; kk < Dn; kk += 8) {
#pragma unroll
        for (int u = 0; u < 8; ++u)
            acc[u] += trow[kk + u] * W[(size_t)(kk + u) * ncol + col];
    }
    float r = ((acc[0] + acc[1]) + (acc[2] + acc[3])) + ((acc[4] + acc[5]) + (acc[6] + acc[7]));
    o[(size_t)row * ncol + col] = r;
}

// ---------------- K2: s_sym[b,i,j] = (q_i.k_j + q_j.k_i)/16, + off-diag sum/sumsq ----------------
// grid (24,24,2), 256 threads, 16x16 output tile each
__global__ void ssym_kernel(const float* __restrict__ q, const float* __restrict__ k,
                            float* __restrict__ ssym, float* __restrict__ stats) {
    __shared__ float qi[16][68], ki[16][68], qj[16][68], kj[16][68];
    __shared__ float red[256];
    const int b = blockIdx.z, it = blockIdx.x, jt = blockIdx.y;
    const int tid = threadIdx.x;
    const int r0 = tid >> 6, c = tid & 63;
#pragma unroll
    for (int p = 0; p < 4; ++p) {
        int row = r0 + 4 * p;
        qi[row][c] = q[((size_t)(b * Nn + it * 16 + row)) * Sn + c];
        ki[row][c] = k[((size_t)(b * Nn + it * 16 + row)) * Sn + c];
        qj[row][c] = q[((size_t)(b * Nn + jt * 16 + row)) * Sn + c];
        kj[row][c] = k[((size_t)(b * Nn + jt * 16 + row)) * Sn + c];
    }
    __syncthreads();
    const int ti = tid >> 4, tj = tid & 15;
    float acc = 0.0f;
#pragma unroll
    for (int dd = 0; dd < Sn; dd += 4) {
        float4 a  = *(const float4*)&qi[ti][dd];
        float4 bb = *(const float4*)&kj[tj][dd];
        float4 cc = *(const float4*)&qj[tj][dd];
        float4 d  = *(const float4*)&ki[ti][dd];
        acc += a.x * bb.x + a.y * bb.y + a.z * bb.z + a.w * bb.w
             + cc.x * d.x + cc.y * d.y + cc.z * d.z + cc.w * d.w;
    }
    const float sval = acc * 0.0625f;
    const int gi = it * 16 + ti, gj = jt * 16 + tj;
    ssym[((size_t)(b * Nn + gi)) * Nn + gj] = sval;
    const float v = (gi == gj) ? 0.0f : sval;

    red[tid] = v;
    __syncthreads();
    for (int off = 128; off > 0; off >>= 1) {
        if (tid < off) red[tid] += red[tid + off];
        __syncthreads();
    }
    const float tot_s = red[0];
    __syncthreads();
    red[tid] = v * v;
    __syncthreads();
    for (int off = 128; off > 0; off >>= 1) {
        if (tid < off) red[tid] += red[tid + off];
        __syncthreads();
    }
    if (tid == 0) {
        atomicAdd(&stats[b * 2 + 0], tot_s);
        atomicAdd(&stats[b * 2 + 1], red[0]);
    }
}

// ---------------- K3: finalize mu, inv_sigma per batch ----------------
__global__ void stats_fin(float* __restrict__ stats) {
    const int b = threadIdx.x;
    if (b < Bn) {
        const float cnt = (float)(Nn * (Nn - 1));
        const float mu = stats[b * 2 + 0] / cnt;
        const float var = stats[b * 2 + 1] / cnt - mu * mu;
        stats[4 + b * 2 + 0] = mu;
        stats[4 + b * 2 + 1] = rsqrtf(var + 1e-6f);
    }
}

// ---------------- K4: m[row] = 1/(sum_j exp(tilde) + EPS) ----------------
__global__ void m_kernel(const float* __restrict__ ssym, const float* __restrict__ stats,
                         const float* __restrict__ a_l, const float* __restrict__ b_l,
                         float* __restrict__ m) {
    const int row = blockIdx.x;
    const int b = row / Nn;
    const float mu = stats[4 + b * 2], isg = stats[5 + b * 2];
    const float a = a_l[0], bb = b_l[0];
    const int tid = threadIdx.x;
    float sum = 0.0f;
    for (int j = tid; j < Nn; j += 128) {
        float til = a * (ssym[(size_t)row * Nn + j] - mu) * isg + bb;
        sum += __expf(1.0f * til);
    }
    __shared__ float red[128];
    red[tid] = sum;
    __syncthreads();
    for (int off = 64; off > 0; off >>= 1) {
        if (tid < off) red[tid] += red[tid + off];
        __syncthreads();
    }
    if (tid == 0) m[row] = 1.0f / (red[0] + 1e-6f);
}

// ---------------- K5: alpha[row,j] = A^2 m_j / (sum_l A_il m_l + DELTA), diag=0 ----------------
__global__ void alpha_kernel(const float* __restrict__ ssym, const float* __restrict__ stats,
                             const float* __restrict__ a_l, const float* __restrict__ b_l,
                             const float* __restrict__ m, float* __restrict__ alpha) {
    const int row = blockIdx.x;
    const int b = row / Nn;
    const int i = row - b * Nn;
    const float mu = stats[4 + b * 2], isg = stats[5 + b * 2];
    const float a = a_l[0], bb = b_l[0];
    const int tid = threadIdx.x;
    float wsum = 0.0f;
    for (int j = tid; j < Nn; j += 128) {
        float til = a * (ssym[(size_t)row * Nn + j] - mu) * isg + bb;
        float A = fast_sigmoid(til);
        wsum += A * m[b * Nn + j];
    }
    __shared__ float red[128];
    red[tid] = wsum;
    __syncthreads();
    for (int off = 64; off > 0; off >>= 1) {
        if (tid < off) red[tid] += red[tid + off];
        __syncthreads();
    }
    const float inv = 1.0f / (red[0] + 1e-6f);
    for (int j = tid; j < Nn; j += 128) {
        float til = a * (ssym[(size_t)row * Nn + j] - mu) * isg + bb;
        float A = fast_sigmoid(til);
        float al = A * A * m[b * Nn + j] * inv;
        alpha[(size_t)row * Nn + j] = (j == i) ? 0.0f : al;
    }
}

// ---------------- K6: main pair kernel ----------------
// One block per (b,i). out[i,d] = t[i,d] - sum_j alpha_ij * sigmoid(kdiff_ij[d]) * (t_i[d]-t_j[d])
// kdiff_ij[d] = sum_r (qd_i[r]kd_j[r] - qd_j[r]kd_i[r]) Vd[r,d]   (GEMM 384x128 * 128x256 per i)
// Thread tiling: 16 tj-groups x 16 td-groups; each thread 8 j (interleaved tj+16q) x 16 d.
__global__ __launch_bounds__(256, 2)
void pair_kernel(const float* __restrict__ t, const float* __restrict__ qd,
                 const float* __restrict__ kd, const float* __restrict__ Vd,
                 const float* __restrict__ alpha, float* __restrict__ out) {
    constexpr int RT = 16;
    constexpr int JT = 128;
    const int bi = blockIdx.x;
    const int b = bi / Nn, i = bi - b * Nn;
    (void)i;
    const int tid = threadIdx.x;
    const int tj = tid >> 4, td = tid & 15;

    // Vd chunk layout: element d stored at [(d>>4)*20 + (d&15)] -> 2-way max bank aliasing
    __shared__ float Vds[RT][320];
    __shared__ float hs[JT][20];   // row stride 20 (16B-aligned), j interleaved reads
    __shared__ float qdi_s[Rn];
    __shared__ float kdi_s[Rn];

    if (tid < Rn) {
        qdi_s[tid] = qd[(size_t)bi * Rn + tid];
        kdi_s[tid] = kd[(size_t)bi * Rn + tid];
    }

    float ti_reg[16];
    {
        const float* tp = &t[(size_t)bi * Dn + td * 16];
        float4 a0 = *(const float4*)(tp + 0);
        float4 a1 = *(const float4*)(tp + 4);
        float4 a2 = *(const float4*)(tp + 8);
        float4 a3 = *(const float4*)(tp + 12);
        ti_reg[0] = a0.x; ti_reg[1] = a0.y; ti_reg[2] = a0.z; ti_reg[3] = a0.w;
        ti_reg[4] = a1.x; ti_reg[5] = a1.y; ti_reg[6] = a1.z; ti_reg[7] = a1.w;
        ti_reg[8] = a2.x; ti_reg[9] = a2.y; ti_reg[10] = a2.z; ti_reg[11] = a2.w;
        ti_reg[12] = a3.x; ti_reg[13] = a3.y; ti_reg[14] = a3.z; ti_reg[15] = a3.w;
    }
    float out_acc[16];
#pragma unroll
    for (int dd = 0; dd < 16; ++dd) out_acc[dd] = 0.0f;

    for (int jt0 = 0; jt0 < Nn; jt0 += JT) {
        float kacc[8][16];
#pragma unroll
        for (int qq = 0; qq < 8; ++qq)
#pragma unroll
            for (int dd = 0; dd < 16; ++dd) kacc[qq][dd] = 0.0f;

        for (int rt = 0; rt < Rn; rt += RT) {
            __syncthreads();   // previous readers done before overwrite
            // stage Vd rows rt..rt+15 (swizzled chunks)
#pragma unroll
            for (int u = 0; u < RT; ++u)
                Vds[u][(tid >> 4) * 20 + (tid & 15)] = Vd[(size_t)(rt + u) * Dn + tid];
            // stage h tile: h[j][r] = qd_i[r]*kd_j[r] - kd_i[r]*qd_j[r]
            {
                const int jj = tid >> 1;
                const int rh = (tid & 1) * 8;
                const int jrow = b * Nn + jt0 + jj;
                float4 kv0 = *(const float4*)&kd[(size_t)jrow * Rn + rt + rh];
                float4 kv1 = *(const float4*)&kd[(size_t)jrow * Rn + rt + rh + 4];
                float4 qv0 = *(const float4*)&qd[(size_t)jrow * Rn + rt + rh];
                float4 qv1 = *(const float4*)&qd[(size_t)jrow * Rn + rt + rh + 4];
                hs[jj][rh + 0] = qdi_s[rt + rh + 0] * kv0.x - kdi_s[rt + rh + 0] * qv0.x;
                hs[jj][rh + 1] = qdi_s[rt + rh + 1] * kv0.y - kdi_s[rt + rh + 1] * qv0.y;
                hs[jj][rh + 2] = qdi_s[rt + rh + 2] * kv0.z - kdi_s[rt + rh + 2] * qv0.z;
                hs[jj][rh + 3] = qdi_s[rt + rh + 3] * kv0.w - kdi_s[rt + rh + 3] * qv0.w;
                hs[jj][rh + 4] = qdi_s[rt + rh + 4] * kv1.x - kdi_s[rt + rh + 4] * qv1.x;
                hs[jj][rh + 5] = qdi_s[rt + rh + 5] * kv1.y - kdi_s[rt + rh + 5] * qv1.y;
                hs[jj][rh + 6] = qdi_s[rt + rh + 6] * kv1.z - kdi_s[rt + rh + 6] * qv1.z;
                hs[jj][rh + 7] = qdi_s[rt + rh + 7] * kv1.w - kdi_s[rt + rh + 7] * qv1.w;
            }
            __syncthreads();
            // register-blocked GEMM: 16 r x (8 j x 16 d) per thread
#pragma unroll
            for (int rr4 = 0; rr4 < 4; ++rr4) {
                const int rr = rr4 * 4;
                float4 hq[8];
#pragma unroll
                for (int qq = 0; qq < 8; ++qq)
                    hq[qq] = *(const float4*)&hs[tj + 16 * qq][rr];
#pragma unroll
                for (int r4 = 0; r4 < 4; ++r4) {
                    const int r = rr + r4;
                    float4 v0 = *(const float4*)&Vds[r][td * 20 + 0];
                    float4 v1 = *(const float4*)&Vds[r][td * 20 + 4];
                    float4 v2 = *(const float4*)&Vds[r][td * 20 + 8];
                    float4 v3 = *(const float4*)&Vds[r][td * 20 + 12];
#pragma unroll
                    for (int qq = 0; qq < 8; ++qq) {
                        const float hv = f4c(hq[qq], r4);
                        kacc[qq][0]  += hv * v0.x; kacc[qq][1]  += hv * v0.y;
                        kacc[qq][2]  += hv * v0.z; kacc[qq][3]  += hv * v0.w;
                        kacc[qq][4]  += hv * v1.x; kacc[qq][5]  += hv * v1.y;
                        kacc[qq][6]  += hv * v1.z; kacc[qq][7]  += hv * v1.w;
                        kacc[qq][8]  += hv * v2.x; kacc[qq][9]  += hv * v2.y;
                        kacc[qq][10] += hv * v2.z; kacc[qq][11] += hv * v2.w;
                        kacc[qq][12] += hv * v3.x; kacc[qq][13] += hv * v3.y;
                        kacc[qq][14] += hv * v3.z; kacc[qq][15] += hv * v3.w;
                    }
                }
            }
        }
        // epilogue for this j-tile
#pragma unroll
        for (int qq = 0; qq < 8; ++qq) {
            const int j = jt0 + tj + 16 * qq;
            const float al = alpha[(size_t)bi * Nn + j];
            const float* tp = &t[(size_t)(b * Nn + j) * Dn + td * 16];
            float4 u0 = *(const float4*)(tp + 0);
            float4 u1 = *(const float4*)(tp + 4);
            float4 u2 = *(const float4*)(tp + 8);
            float4 u3 = *(const float4*)(tp + 12);
            out_acc[0]  += al * fast_sigmoid(kacc[qq][0])  * (ti_reg[0]  - u0.x);
            out_acc[1]  += al * fast_sigmoid(kacc[qq][1])  * (ti_reg[1]  - u0.y);
            out_acc[2]  += al * fast_sigmoid(kacc[qq][2])  * (ti_reg[2]  - u0.z);
            out_acc[3]  += al * fast_sigmoid(kacc[qq][3])  * (ti_reg[3]  - u0.w);
            out_acc[4]  += al * fast_sigmoid(kacc[qq][4])  * (ti_reg[4]  - u1.x);
            out_acc[5]  += al * fast_sigmoid(kacc[qq][5])  * (ti_reg[5]  - u1.y);
            out_acc[6]  += al * fast_sigmoid(kacc[qq][6])  * (ti_reg[6]  - u1.z);
            out_acc[7]  += al * fast_sigmoid(kacc[qq][7])  * (ti_reg[7]  - u1.w);
            out_acc[8]  += al * fast_sigmoid(kacc[qq][8])  * (ti_reg[8]  - u2.x);
            out_acc[9]  += al * fast_sigmoid(kacc[qq][9])  * (ti_reg[9]  - u2.y);
            out_acc[10] += al * fast_sigmoid(kacc[qq][10]) * (ti_reg[10] - u2.z);
            out_acc[11] += al * fast_sigmoid(kacc[qq][11]) * (ti_reg[11] - u2.w);
            out_acc[12] += al * fast_sigmoid(kacc[qq][12]) * (ti_reg[12] - u3.x);
            out_acc[13] += al * fast_sigmoid(kacc[qq][13]) * (ti_reg[13] - u3.y);
            out_acc[14] += al * fast_sigmoid(kacc[qq][14]) * (ti_reg[14] - u3.z);
            out_acc[15] += al * fast_sigmoid(kacc[qq][15]) * (ti_reg[15] - u3.w);
        }
    }
    // reduce partial sums across the 16 tj-groups (reuse Vds as scratch: 16x256)
    __syncthreads();
    float* red = (float*)Vds;
#pragma unroll
    for (int u = 0; u < 4; ++u) {
        float4 w = make_float4(out_acc[u * 4 + 0], out_acc[u * 4 + 1],
                               out_acc[u * 4 + 2], out_acc[u * 4 + 3]);
        *(float4*)&red[tj * 256 + td * 16 + u * 4] = w;
    }
    __syncthreads();
    float ssum = 0.0f;
#pragma unroll
    for (int g2 = 0; g2 < 16; ++g2) ssum += red[g2 * 256 + tid];
    out[(size_t)bi * Dn + tid] = t[(size_t)bi * Dn + tid] - ssum;
}

extern "C" void kernel_launch(void* const* d_in, const int* in_sizes, int n_in,
                              void* d_out, int out_size, void* d_ws, size_t ws_size,
                              hipStream_t stream) {
    const float* t   = (const float*)d_in[0];
    const float* Qd  = (const float*)d_in[1];
    const float* Kd  = (const float*)d_in[2];
    const float* Vd  = (const float*)d_in[3];
    const float* Qs  = (const float*)d_in[4];
    const float* Ks  = (const float*)d_in[5];
    const float* a_l = (const float*)d_in[6];
    const float* b_l = (const float*)d_in[7];
    float* out = (float*)d_out;
    float* ws  = (float*)d_ws;

    float* q     = ws;                         // 768*64
    float* k     = q + BNn * Sn;               // 768*64
    float* qdp   = k + BNn * Sn;               // 768*128
    float* kdp   = qdp + BNn * Rn;             // 768*128
    float* ssym  = kdp + BNn * Rn;             // 768*384
    float* alpha = ssym + (size_t)BNn * Nn;    // 768*384
    float* m     = alpha + (size_t)BNn * Nn;   // 768
    float* stats = m + BNn;                    // 8

    hipLaunchKernelGGL(zero_stats, dim3(1), dim3(64), 0, stream, stats);
    hipLaunchKernelGGL(proj_kernel, dim3(BNn), dim3(384), 0, stream,
                       t, Qd, Kd, Qs, Ks, q, k, qdp, kdp);
    hipLaunchKernelGGL(ssym_kernel, dim3(Nn / 16, Nn / 16, Bn), dim3(256), 0, stream,
                       q, k, ssym, stats);
    hipLaunchKernelGGL(stats_fin, dim3(1), dim3(64), 0, stream, stats);
    hipLaunchKernelGGL(m_kernel, dim3(BNn), dim3(128), 0, stream, ssym, stats, a_l, b_l, m);
    hipLaunchKernelGGL(alpha_kernel, dim3(BNn), dim3(128), 0, stream, ssym, stats, a_l, b_l, m, alpha);
    hipLaunchKernelGGL(pair_kernel, dim3(BNn), dim3(256), 0, stream, t, qdp, kdp, Vd, alpha, out);
}

// Round 2
// 197.737 us; speedup vs baseline: 2.2087x; 2.2087x over previous
//
#include <hip/hip_runtime.h>

#define Bn 2
#define Nn 384
#define Dn 256
#define Rn 128
#define Sn 64
#define BNn (Bn*Nn)

typedef short short8 __attribute__((ext_vector_type(8)));
typedef float f32x4 __attribute__((ext_vector_type(4)));
typedef unsigned int uint;
typedef unsigned short ushort;

static __device__ __forceinline__ float fast_sigmoid(float x) {
    return __builtin_amdgcn_rcpf(1.0f + __expf(-x));
}

static __device__ __forceinline__ ushort f2bf(float f) {
    uint u = __float_as_uint(f);
    uint r = (u + 0x7fffu + ((u >> 16) & 1u)) >> 16;   // RNE
    return (ushort)r;
}
static __device__ __forceinline__ float bf2f(ushort u) {
    return __uint_as_float(((uint)u) << 16);
}

// ---------------- K0: zero the stats accumulator area ----------------
__global__ void zero_stats(float* __restrict__ stats) {
    if (threadIdx.x < 8) stats[threadIdx.x] = 0.0f;
}

// ---------------- K1: projections. 4 rows per block, 192 blocks x 384 thr ----------------
// q,k fp32 (for ssym); qd,kd written as bf16 (for pair kernel)
__global__ void proj_kernel(const float* __restrict__ t,
                            const float* __restrict__ Qd, const float* __restrict__ Kd,
                            const float* __restrict__ Qs, const float* __restrict__ Ks,
                            float* __restrict__ q, float* __restrict__ k,
                            ushort* __restrict__ qdb, ushort* __restrict__ kdb) {
    __shared__ float trow[4][Dn];
    const int r0 = blockIdx.x * 4;
    const int tid = threadIdx.x;
    for (int idx = tid; idx < 4 * Dn; idx += 384)
        trow[idx >> 8][idx & 255] = t[(size_t)(r0 + (idx >> 8)) * Dn + (idx & 255)];
    __syncthreads();
    const float* W;
    float* of = nullptr;
    ushort* ob = nullptr;
    int ncol, col;
    if (tid < 64)       { W = Qs; of = q;   ncol = 64;  col = tid; }
    else if (tid < 128) { W = Ks; of = k;   ncol = 64;  col = tid - 64; }
    else if (tid < 256) { W = Qd; ob = qdb; ncol = 128; col = tid - 128; }
    else                { W = Kd; ob = kdb; ncol = 128; col = tid - 256; }
    float a0 = 0.f, a1 = 0.f, a2 = 0.f, a3 = 0.f;
    for (int kk = 0; kk < Dn; kk += 4) {
        float4 t0 = *(const float4*)&trow[0][kk];
        float4 t1 = *(const float4*)&trow[1][kk];
        float4 t2 = *(const float4*)&trow[2][kk];
        float4 t3 = *(const float4*)&trow[3][kk];
        float w0 = W[(size_t)(kk + 0) * ncol + col];
        float w1 = W[(size_t)(kk + 1) * ncol + col];
        float w2 = W[(size_t)(kk + 2) * ncol + col];
        float w3 = W[(size_t)(kk + 3) * ncol + col];
        a0 += t0.x * w0 + t0.y * w1 + t0.z * w2 + t0.w * w3;
        a1 += t1.x * w0 + t1.y * w1 + t1.z * w2 + t1.w * w3;
        a2 += t2.x * w0 + t2.y * w1 + t2.z * w2 + t2.w * w3;
        a3 += t3.x * w0 + t3.y * w1 + t3.z * w2 + t3.w * w3;
    }
    if (of) {
        of[(size_t)(r0 + 0) * ncol + col] = a0;
        of[(size_t)(r0 + 1) * ncol + col] = a1;
        of[(size_t)(r0 + 2) * ncol + col] = a2;
        of[(size_t)(r0 + 3) * ncol + col] = a3;
    } else {
        ob[(size_t)(r0 + 0) * ncol + col] = f2bf(a0);
        ob[(size_t)(r0 + 1) * ncol + col] = f2bf(a1);
        ob[(size_t)(r0 + 2) * ncol + col] = f2bf(a2);
        ob[(size_t)(r0 + 3) * ncol + col] = f2bf(a3);
    }
}

// ---------------- K1b: VdT[d][r] = bf16(Vd[r][d]) ----------------
__global__ void prep_vdt(const float* __restrict__ Vd, ushort* __restrict__ VdT) {
    const int idx = blockIdx.x * 256 + threadIdx.x;   // 32768
    const int d = idx >> 7, r = idx & 127;
    VdT[idx] = f2bf(Vd[(size_t)r * Dn + d]);
}

// ---------------- K2: s_sym + off-diag stats ----------------
__global__ void ssym_kernel(const float* __restrict__ q, const float* __restrict__ k,
                            float* __restrict__ ssym, float* __restrict__ stats) {
    __shared__ float qi[16][68], ki[16][68], qj[16][68], kj[16][68];
    __shared__ float red[256];
    const int b = blockIdx.z, it = blockIdx.x, jt = blockIdx.y;
    const int tid = threadIdx.x;
    const int r0 = tid >> 6, c = tid & 63;
#pragma unroll
    for (int p = 0; p < 4; ++p) {
        int row = r0 + 4 * p;
        qi[row][c] = q[((size_t)(b * Nn + it * 16 + row)) * Sn + c];
        ki[row][c] = k[((size_t)(b * Nn + it * 16 + row)) * Sn + c];
        qj[row][c] = q[((size_t)(b * Nn + jt * 16 + row)) * Sn + c];
        kj[row][c] = k[((size_t)(b * Nn + jt * 16 + row)) * Sn + c];
    }
    __syncthreads();
    const int ti = tid >> 4, tj = tid & 15;
    float acc = 0.0f;
#pragma unroll
    for (int dd = 0; dd < Sn; dd += 4) {
        float4 a  = *(const float4*)&qi[ti][dd];
        float4 bb = *(const float4*)&kj[tj][dd];
        float4 cc = *(const float4*)&qj[tj][dd];
        float4 d  = *(const float4*)&ki[ti][dd];
        acc += a.x * bb.x + a.y * bb.y + a.z * bb.z + a.w * bb.w
             + cc.x * d.x + cc.y * d.y + cc.z * d.z + cc.w * d.w;
    }
    const float sval = acc * 0.0625f;
    const int gi = it * 16 + ti, gj = jt * 16 + tj;
    ssym[((size_t)(b * Nn + gi)) * Nn + gj] = sval;
    const float v = (gi == gj) ? 0.0f : sval;

    red[tid] = v;
    __syncthreads();
    for (int off = 128; off > 0; off >>= 1) {
        if (tid < off) red[tid] += red[tid + off];
        __syncthreads();
    }
    const float tot_s = red[0];
    __syncthreads();
    red[tid] = v * v;
    __syncthreads();
    for (int off = 128; off > 0; off >>= 1) {
        if (tid < off) red[tid] += red[tid + off];
        __syncthreads();
    }
    if (tid == 0) {
        atomicAdd(&stats[b * 2 + 0], tot_s);
        atomicAdd(&stats[b * 2 + 1], red[0]);
    }
}

// ---------------- K3: finalize mu, inv_sigma ----------------
__global__ void stats_fin(float* __restrict__ stats) {
    const int b = threadIdx.x;
    if (b < Bn) {
        const float cnt = (float)(Nn * (Nn - 1));
        const float mu = stats[b * 2 + 0] / cnt;
        const float var = stats[b * 2 + 1] / cnt - mu * mu;
        stats[4 + b * 2 + 0] = mu;
        stats[4 + b * 2 + 1] = rsqrtf(var + 1e-6f);
    }
}

// ---------------- K4: m[row] ----------------
__global__ void m_kernel(const float* __restrict__ ssym, const float* __restrict__ stats,
                         const float* __restrict__ a_l, const float* __restrict__ b_l,
                         float* __restrict__ m) {
    const int row = blockIdx.x;
    const int b = row / Nn;
    const float mu = stats[4 + b * 2], isg = stats[5 + b * 2];
    const float a = a_l[0], bb = b_l[0];
    const int tid = threadIdx.x;
    float sum = 0.0f;
    for (int j = tid; j < Nn; j += 128) {
        float til = a * (ssym[(size_t)row * Nn + j] - mu) * isg + bb;
        sum += __expf(til);
    }
    __shared__ float red[128];
    red[tid] = sum;
    __syncthreads();
    for (int off = 64; off > 0; off >>= 1) {
        if (tid < off) red[tid] += red[tid + off];
        __syncthreads();
    }
    if (tid == 0) m[row] = 1.0f / (red[0] + 1e-6f);
}

// ---------------- K5: alpha ----------------
__global__ void alpha_kernel(const float* __restrict__ ssym, const float* __restrict__ stats,
                             const float* __restrict__ a_l, const float* __restrict__ b_l,
                             const float* __restrict__ m, float* __restrict__ alpha) {
    const int row = blockIdx.x;
    const int b = row / Nn;
    const int i = row - b * Nn;
    const float mu = stats[4 + b * 2], isg = stats[5 + b * 2];
    const float a = a_l[0], bb = b_l[0];
    const int tid = threadIdx.x;
    float wsum = 0.0f;
    for (int j = tid; j < Nn; j += 128) {
        float til = a * (ssym[(size_t)row * Nn + j] - mu) * isg + bb;
        float A = fast_sigmoid(til);
        wsum += A * m[b * Nn + j];
    }
    __shared__ float red[128];
    red[tid] = wsum;
    __syncthreads();
    for (int off = 64; off > 0; off >>= 1) {
        if (tid < off) red[tid] += red[tid + off];
        __syncthreads();
    }
    const float inv = 1.0f / (red[0] + 1e-6f);
    for (int j = tid; j < Nn; j += 128) {
        float til = a * (ssym[(size_t)row * Nn + j] - mu) * isg + bb;
        float A = fast_sigmoid(til);
        float al = A * A * m[b * Nn + j] * inv;
        alpha[(size_t)row * Nn + j] = (j == i) ? 0.0f : al;
    }
}

// ---------------- K6: MFMA pair kernel ----------------
// One block per (b,i), 256 thr = 4 waves. kappa_diff[d][j] = sum_r VdT[d][r]*h[j][r],
// computed as MFMA D = A(VdT d x r) * B(h r x j). Wave w owns d in [64w, 64w+64).
// C-layout: row (d) = quad*4+reg (4 CONSECUTIVE d per lane -> float4 t_j loads),
// col (j) = lane&15. Output j-reduce = shuffle over 16 lanes, once per block.
__global__ __launch_bounds__(256, 3)
void pair_kernel(const float* __restrict__ t, const ushort* __restrict__ qdb,
                 const ushort* __restrict__ kdb, const ushort* __restrict__ VdT,
                 const float* __restrict__ alpha, float* __restrict__ out) {
    __shared__ ushort h_s[128][136];     // h[j][r] bf16, row pad 136 (odd 16B stride)
    __shared__ float alpha_s[Nn];
    __shared__ float qdi_s[Rn], kdi_s[Rn];

    const int bi = blockIdx.x;
    const int b = bi / Nn;
    const int tid = threadIdx.x;
    const int wave = tid >> 6, lane = tid & 63;
    const int ln = lane & 15, quad = lane >> 4;
    const int wd0 = wave * 64;

    for (int idx = tid; idx < Nn; idx += 256) alpha_s[idx] = alpha[(size_t)bi * Nn + idx];
    if (tid < Rn) {
        qdi_s[tid] = bf2f(qdb[(size_t)bi * Rn + tid]);
        kdi_s[tid] = bf2f(kdb[(size_t)bi * Rn + tid]);
    }

    // A-fragments of VdT (constant over j) : vf[dt][ks], d = wd0+dt*16+ln, k = ks*32+quad*8+e
    short8 vf[4][4];
#pragma unroll
    for (int dt = 0; dt < 4; ++dt)
#pragma unroll
        for (int ks = 0; ks < 4; ++ks)
            vf[dt][ks] = *(const short8*)&VdT[(size_t)(wd0 + dt * 16 + ln) * Rn + ks * 32 + quad * 8];

    float4 tiv[4];
#pragma unroll
    for (int dt = 0; dt < 4; ++dt)
        tiv[dt] = *(const float4*)&t[(size_t)bi * Dn + wd0 + dt * 16 + quad * 4];

    float4 outac[4];
#pragma unroll
    for (int dt = 0; dt < 4; ++dt) outac[dt] = make_float4(0.f, 0.f, 0.f, 0.f);

    __syncthreads();

    for (int jt0 = 0; jt0 < Nn; jt0 += 128) {
        // ---- stage h tile: h[j][r] = qd_i[r]*kd_j[r] - kd_i[r]*qd_j[r], bf16 ----
        {
            const int jj = tid >> 1;
            const int r0 = (tid & 1) * 64;
            const size_t rowj = (size_t)(b * Nn + jt0 + jj) * Rn;
            const uint4* qp = (const uint4*)(qdb + rowj + r0);
            const uint4* kp = (const uint4*)(kdb + rowj + r0);
#pragma unroll
            for (int c = 0; c < 8; ++c) {
                uint4 qv = qp[c], kv = kp[c];
                uint pk[4];
#pragma unroll
                for (int p = 0; p < 4; ++p) {
                    uint qu = (&qv.x)[p], ku = (&kv.x)[p];
                    float qlo = __uint_as_float(qu << 16);
                    float qhi = __uint_as_float(qu & 0xffff0000u);
                    float klo = __uint_as_float(ku << 16);
                    float khi = __uint_as_float(ku & 0xffff0000u);
                    const int r = r0 + c * 8 + p * 2;
                    float h0 = qdi_s[r]     * klo - kdi_s[r]     * qlo;
                    float h1 = qdi_s[r + 1] * khi - kdi_s[r + 1] * qhi;
                    pk[p] = (uint)f2bf(h0) | ((uint)f2bf(h1) << 16);
                }
                uint4 w; w.x = pk[0]; w.y = pk[1]; w.z = pk[2]; w.w = pk[3];
                *(uint4*)&h_s[jj][r0 + c * 8] = w;
            }
        }
        __syncthreads();

        // ---- MFMA + epilogue over 8 j-subtiles x 4 d-tiles ----
#pragma unroll 1
        for (int jsub = 0; jsub < 8; ++jsub) {
            short8 hf[4];
#pragma unroll
            for (int ks = 0; ks < 4; ++ks)
                hf[ks] = *(const short8*)&h_s[jsub * 16 + ln][ks * 32 + quad * 8];
            const int j = jt0 + jsub * 16 + ln;
            const float al = alpha_s[j];
            const size_t trow = (size_t)(b * Nn + j) * Dn;
#pragma unroll
            for (int dt = 0; dt < 4; ++dt) {
                float4 tj = *(const float4*)&t[trow + wd0 + dt * 16 + quad * 4];
                f32x4 acc = {0.f, 0.f, 0.f, 0.f};
#pragma unroll
                for (int ks = 0; ks < 4; ++ks)
                    acc = __builtin_amdgcn_mfma_f32_16x16x32_bf16(vf[dt][ks], hf[ks], acc, 0, 0, 0);
                outac[dt].x += al * fast_sigmoid(acc[0]) * (tiv[dt].x - tj.x);
                outac[dt].y += al * fast_sigmoid(acc[1]) * (tiv[dt].y - tj.y);
                outac[dt].z += al * fast_sigmoid(acc[2]) * (tiv[dt].z - tj.z);
                outac[dt].w += al * fast_sigmoid(acc[3]) * (tiv[dt].w - tj.w);
            }
        }
        __syncthreads();
    }

    // ---- reduce over the 16 j-lanes, write 64 d per wave ----
#pragma unroll
    for (int dt = 0; dt < 4; ++dt) {
        float4 v = outac[dt];
#pragma unroll
        for (int mask = 1; mask < 16; mask <<= 1) {
            v.x += __shfl_xor(v.x, mask);
            v.y += __shfl_xor(v.y, mask);
            v.z += __shfl_xor(v.z, mask);
            v.w += __shfl_xor(v.w, mask);
        }
        if (ln == 0) {
            float4 o;
            o.x = tiv[dt].x - v.x;
            o.y = tiv[dt].y - v.y;
            o.z = tiv[dt].z - v.z;
            o.w = tiv[dt].w - v.w;
            *(float4*)&out[(size_t)bi * Dn + wd0 + dt * 16 + quad * 4] = o;
        }
    }
}

extern "C" void kernel_launch(void* const* d_in, const int* in_sizes, int n_in,
                              void* d_out, int out_size, void* d_ws, size_t ws_size,
                              hipStream_t stream) {
    const float* t   = (const float*)d_in[0];
    const float* Qd  = (const float*)d_in[1];
    const float* Kd  = (const float*)d_in[2];
    const float* Vd  = (const float*)d_in[3];
    const float* Qs  = (const float*)d_in[4];
    const float* Ks  = (const float*)d_in[5];
    const float* a_l = (const float*)d_in[6];
    const float* b_l = (const float*)d_in[7];
    float* out = (float*)d_out;
    float* ws  = (float*)d_ws;

    float* q     = ws;                          // 768*64
    float* k     = q + BNn * Sn;                // 768*64
    float* ssym  = k + BNn * Sn;                // 768*384
    float* alpha = ssym + (size_t)BNn * Nn;     // 768*384
    float* m     = alpha + (size_t)BNn * Nn;    // 768
    float* stats = m + BNn;                     // 8
    ushort* qdb  = (ushort*)(stats + 8);        // 768*128 bf16
    ushort* kdb  = qdb + (size_t)BNn * Rn;      // 768*128 bf16
    ushort* VdT  = kdb + (size_t)BNn * Rn;      // 256*128 bf16

    hipLaunchKernelGGL(zero_stats, dim3(1), dim3(64), 0, stream, stats);
    hipLaunchKernelGGL(proj_kernel, dim3(BNn / 4), dim3(384), 0, stream,
                       t, Qd, Kd, Qs, Ks, q, k, qdb, kdb);
    hipLaunchKernelGGL(prep_vdt, dim3(128), dim3(256), 0, stream, Vd, VdT);
    hipLaunchKernelGGL(ssym_kernel, dim3(Nn / 16, Nn / 16, Bn), dim3(256), 0, stream,
                       q, k, ssym, stats);
    hipLaunchKernelGGL(stats_fin, dim3(1), dim3(64), 0, stream, stats);
    hipLaunchKernelGGL(m_kernel, dim3(BNn), dim3(128), 0, stream, ssym, stats, a_l, b_l, m);
    hipLaunchKernelGGL(alpha_kernel, dim3(BNn), dim3(128), 0, stream, ssym, stats, a_l, b_l, m, alpha);
    hipLaunchKernelGGL(pair_kernel, dim3(BNn), dim3(256), 0, stream,
                       t, qdb, kdb, VdT, alpha, out);
}

// Round 4
// 187.198 us; speedup vs baseline: 2.3331x; 1.0563x over previous
//
#include <hip/hip_runtime.h>

#define Bn 2
#define Nn 384
#define Dn 256
#define Rn 128
#define Sn 64
#define BNn (Bn*Nn)
#define NEG_LOG2E -1.44269504088896f

typedef short short8 __attribute__((ext_vector_type(8)));
typedef float f32x4 __attribute__((ext_vector_type(4)));
typedef unsigned int uint;
typedef unsigned short ushort;

static __device__ __forceinline__ float fast_sigmoid(float x) {
    return __builtin_amdgcn_rcpf(1.0f + __expf(-x));
}
static __device__ __forceinline__ ushort f2bf(float f) {
    uint u = __float_as_uint(f);
    uint r = (u + 0x7fffu + ((u >> 16) & 1u)) >> 16;   // RNE
    return (ushort)r;
}
static __device__ __forceinline__ float bf2f(ushort u) {
    return __uint_as_float(((uint)u) << 16);
}

// ================= K1: prep = zero-stats + projections + VdT transpose =================
// grid 320 x 256. Blocks 0..191: proj of 4 t-rows each. Blocks 192..319: VdT prep.
__global__ __launch_bounds__(256)
void prep_kernel(const float* __restrict__ t,
                 const float* __restrict__ Qd, const float* __restrict__ Kd,
                 const float* __restrict__ Vd,
                 const float* __restrict__ Qs, const float* __restrict__ Ks,
                 float* __restrict__ q, float* __restrict__ k,
                 ushort* __restrict__ qdb, ushort* __restrict__ kdb,
                 ushort* __restrict__ VdT, float* __restrict__ stats) {
    const int bi = blockIdx.x;
    const int tid = threadIdx.x;
    if (bi >= 192) {
        // VdT[d][r] = bf16(-log2(e) * Vd[r][d])  (pre-scaled for exp2-based gate)
        const int idx = (bi - 192) * 256 + tid;       // 0..32767
        const int d = idx >> 7, r = idx & 127;
        VdT[idx] = f2bf(NEG_LOG2E * Vd[(size_t)r * Dn + d]);
        if (bi == 319 && tid < 4) stats[tid] = 0.0f;
        return;
    }
    __shared__ float trow[4][Dn];
    const int r0 = bi * 4;
    for (int idx = tid; idx < 4 * Dn; idx += 256)
        trow[idx >> 8][idx & 255] = t[(size_t)r0 * Dn + idx];
    __syncthreads();
    // qd / kd (bf16): all 256 threads
    {
        const float* W = (tid < 128) ? Qd : Kd;
        ushort* ob = (tid < 128) ? qdb : kdb;
        const int col = tid & 127;
        float a0 = 0.f, a1 = 0.f, a2 = 0.f, a3 = 0.f;
        for (int kk = 0; kk < Dn; kk += 4) {
            float4 t0 = *(const float4*)&trow[0][kk];
            float4 t1 = *(const float4*)&trow[1][kk];
            float4 t2 = *(const float4*)&trow[2][kk];
            float4 t3 = *(const float4*)&trow[3][kk];
            float w0 = W[(size_t)(kk + 0) * 128 + col];
            float w1 = W[(size_t)(kk + 1) * 128 + col];
            float w2 = W[(size_t)(kk + 2) * 128 + col];
            float w3 = W[(size_t)(kk + 3) * 128 + col];
            a0 += t0.x * w0 + t0.y * w1 + t0.z * w2 + t0.w * w3;
            a1 += t1.x * w0 + t1.y * w1 + t1.z * w2 + t1.w * w3;
            a2 += t2.x * w0 + t2.y * w1 + t2.z * w2 + t2.w * w3;
            a3 += t3.x * w0 + t3.y * w1 + t3.z * w2 + t3.w * w3;
        }
        ob[(size_t)(r0 + 0) * 128 + col] = f2bf(a0);
        ob[(size_t)(r0 + 1) * 128 + col] = f2bf(a1);
        ob[(size_t)(r0 + 2) * 128 + col] = f2bf(a2);
        ob[(size_t)(r0 + 3) * 128 + col] = f2bf(a3);
    }
    // q / k (fp32): threads < 128
    if (tid < 128) {
        const float* W = (tid < 64) ? Qs : Ks;
        float* of = (tid < 64) ? q : k;
        const int col = tid & 63;
        float a0 = 0.f, a1 = 0.f, a2 = 0.f, a3 = 0.f;
        for (int kk = 0; kk < Dn; kk += 4) {
            float4 t0 = *(const float4*)&trow[0][kk];
            float4 t1 = *(const float4*)&trow[1][kk];
            float4 t2 = *(const float4*)&trow[2][kk];
            float4 t3 = *(const float4*)&trow[3][kk];
            float w0 = W[(size_t)(kk + 0) * 64 + col];
            float w1 = W[(size_t)(kk + 1) * 64 + col];
            float w2 = W[(size_t)(kk + 2) * 64 + col];
            float w3 = W[(size_t)(kk + 3) * 64 + col];
            a0 += t0.x * w0 + t0.y * w1 + t0.z * w2 + t0.w * w3;
            a1 += t1.x * w0 + t1.y * w1 + t1.z * w2 + t1.w * w3;
            a2 += t2.x * w0 + t2.y * w1 + t2.z * w2 + t2.w * w3;
            a3 += t3.x * w0 + t3.y * w1 + t3.z * w2 + t3.w * w3;
        }
        of[(size_t)(r0 + 0) * 64 + col] = a0;
        of[(size_t)(r0 + 1) * 64 + col] = a1;
        of[(size_t)(r0 + 2) * 64 + col] = a2;
        of[(size_t)(r0 + 3) * 64 + col] = a3;
    }
}

// ================= K2: s_sym + off-diag stats =================
__global__ __launch_bounds__(256)
void ssym_kernel(const float* __restrict__ q, const float* __restrict__ k,
                 float* __restrict__ ssym, float* __restrict__ stats) {
    __shared__ float qi[16][68], ki[16][68], qj[16][68], kj[16][68];
    __shared__ float red[256];
    const int b = blockIdx.z, it = blockIdx.x, jt = blockIdx.y;
    const int tid = threadIdx.x;
    const int r0 = tid >> 6, c = tid & 63;
#pragma unroll
    for (int p = 0; p < 4; ++p) {
        int row = r0 + 4 * p;
        qi[row][c] = q[((size_t)(b * Nn + it * 16 + row)) * Sn + c];
        ki[row][c] = k[((size_t)(b * Nn + it * 16 + row)) * Sn + c];
        qj[row][c] = q[((size_t)(b * Nn + jt * 16 + row)) * Sn + c];
        kj[row][c] = k[((size_t)(b * Nn + jt * 16 + row)) * Sn + c];
    }
    __syncthreads();
    const int ti = tid >> 4, tj = tid & 15;
    float acc = 0.0f;
#pragma unroll
    for (int dd = 0; dd < Sn; dd += 4) {
        float4 a  = *(const float4*)&qi[ti][dd];
        float4 bb = *(const float4*)&kj[tj][dd];
        float4 cc = *(const float4*)&qj[tj][dd];
        float4 d  = *(const float4*)&ki[ti][dd];
        acc += a.x * bb.x + a.y * bb.y + a.z * bb.z + a.w * bb.w
             + cc.x * d.x + cc.y * d.y + cc.z * d.z + cc.w * d.w;
    }
    const float sval = acc * 0.0625f;
    const int gi = it * 16 + ti, gj = jt * 16 + tj;
    ssym[((size_t)(b * Nn + gi)) * Nn + gj] = sval;
    const float v = (gi == gj) ? 0.0f : sval;

    red[tid] = v;
    __syncthreads();
    for (int off = 128; off > 0; off >>= 1) {
        if (tid < off) red[tid] += red[tid + off];
        __syncthreads();
    }
    const float tot_s = red[0];
    __syncthreads();
    red[tid] = v * v;
    __syncthreads();
    for (int off = 128; off > 0; off >>= 1) {
        if (tid < off) red[tid] += red[tid + off];
        __syncthreads();
    }
    if (tid == 0) {
        atomicAdd(&stats[b * 2 + 0], tot_s);
        atomicAdd(&stats[b * 2 + 1], red[0]);
    }
}

// ================= K3: m[row] (stats finalized inline) =================
__global__ __launch_bounds__(256)
void m_kernel(const float* __restrict__ ssym, const float* __restrict__ stats,
              const float* __restrict__ a_l, const float* __restrict__ b_l,
              float* __restrict__ m) {
    __shared__ float red[256];
    const int row = blockIdx.x;
    const int b = row / Nn;
    const float cnt_inv = 1.0f / (float)(Nn * (Nn - 1));
    const float mu = stats[b * 2 + 0] * cnt_inv;
    const float var = stats[b * 2 + 1] * cnt_inv - mu * mu;
    const float isg = rsqrtf(var + 1e-6f);
    const float a = a_l[0], bbias = b_l[0];
    const int tid = threadIdx.x;
    float sum = __expf(a * (ssym[(size_t)row * Nn + tid] - mu) * isg + bbias);
    if (tid < 128)
        sum += __expf(a * (ssym[(size_t)row * Nn + 256 + tid] - mu) * isg + bbias);
    red[tid] = sum;
    __syncthreads();
    for (int off = 128; off > 0; off >>= 1) {
        if (tid < off) red[tid] += red[tid + off];
        __syncthreads();
    }
    if (tid == 0) m[row] = 1.0f / (red[0] + 1e-6f);
}

// ================= K4: pair kernel (alpha inline) =================
// One block per (b,i), 256 thr = 4 waves. acc = -log2e * (kappa_ij - kappa_ji)[d]
// via MFMA A(VdT d x r) * B(h r x j); gate = 1/(1+2^acc) = sigmoid(kappa_diff).
__global__ __launch_bounds__(256, 3)
void pair_kernel(const float* __restrict__ t, const float* __restrict__ ssym,
                 const float* __restrict__ mptr, const float* __restrict__ stats,
                 const float* __restrict__ a_l, const float* __restrict__ b_l,
                 const ushort* __restrict__ qdb, const ushort* __restrict__ kdb,
                 const ushort* __restrict__ VdT, float* __restrict__ out) {
    __shared__ ushort h_s[128][136];     // h[j][r] bf16, row pad 136
    __shared__ float alpha_s[Nn];
    __shared__ float qdi_s[Rn], kdi_s[Rn];
    __shared__ float red[256];

    const int bi = blockIdx.x;
    const int b = bi / Nn;
    const int i = bi - b * Nn;
    const int tid = threadIdx.x;
    const int wave = tid >> 6, lane = tid & 63;
    const int ln = lane & 15, quad = lane >> 4;
    const int wd0 = wave * 64;

    // ---- inline alpha row ----
    {
        const float cnt_inv = 1.0f / (float)(Nn * (Nn - 1));
        const float mu = stats[b * 2 + 0] * cnt_inv;
        const float var = stats[b * 2 + 1] * cnt_inv - mu * mu;
        const float isg = rsqrtf(var + 1e-6f);
        const float a = a_l[0], bbias = b_l[0];
        float A0, am0, A1 = 0.f, am1 = 0.f;
        {
            float s0 = ssym[(size_t)bi * Nn + tid];
            A0 = fast_sigmoid(a * (s0 - mu) * isg + bbias);
            am0 = A0 * mptr[b * Nn + tid];
        }
        if (tid < 128) {
            float s1 = ssym[(size_t)bi * Nn + 256 + tid];
            A1 = fast_sigmoid(a * (s1 - mu) * isg + bbias);
            am1 = A1 * mptr[b * Nn + 256 + tid];
        }
        red[tid] = am0 + am1;
        __syncthreads();
        for (int off = 128; off > 0; off >>= 1) {
            if (tid < off) red[tid] += red[tid + off];
            __syncthreads();
        }
        const float inv = 1.0f / (red[0] + 1e-6f);
        alpha_s[tid] = (tid == i) ? 0.f : A0 * am0 * inv;
        if (tid < 128)
            alpha_s[256 + tid] = ((256 + tid) == i) ? 0.f : A1 * am1 * inv;
    }
    if (tid < Rn) {
        qdi_s[tid] = bf2f(qdb[(size_t)bi * Rn + tid]);
        kdi_s[tid] = bf2f(kdb[(size_t)bi * Rn + tid]);
    }

    // A-fragments of VdT (constant over j)
    short8 vf[4][4];
#pragma unroll
    for (int dt = 0; dt < 4; ++dt)
#pragma unroll
        for (int ks = 0; ks < 4; ++ks)
            vf[dt][ks] = *(const short8*)&VdT[(size_t)(wd0 + dt * 16 + ln) * Rn + ks * 32 + quad * 8];

    float4 tiv[4];
#pragma unroll
    for (int dt = 0; dt < 4; ++dt)
        tiv[dt] = *(const float4*)&t[(size_t)bi * Dn + wd0 + dt * 16 + quad * 4];

    float4 outac[4];
#pragma unroll
    for (int dt = 0; dt < 4; ++dt) outac[dt] = make_float4(0.f, 0.f, 0.f, 0.f);

    for (int jt0 = 0; jt0 < Nn; jt0 += 128) {
        __syncthreads();   // prev readers done; covers alpha/qdi writes on iter 0
        // ---- stage h tile: h[j][r] = qd_i[r]*kd_j[r] - kd_i[r]*qd_j[r] (bf16) ----
        {
            const int jj = tid >> 1;
            const int r0s = (tid & 1) * 64;
            const size_t rowj = (size_t)(b * Nn + jt0 + jj) * Rn;
            const uint4* qp = (const uint4*)(qdb + rowj + r0s);
            const uint4* kp = (const uint4*)(kdb + rowj + r0s);
#pragma unroll
            for (int c = 0; c < 8; ++c) {
                uint4 qv = qp[c], kv = kp[c];
                uint pk[4];
#pragma unroll
                for (int p = 0; p < 4; ++p) {
                    uint qu = (&qv.x)[p], ku = (&kv.x)[p];
                    float qlo = __uint_as_float(qu << 16);
                    float qhi = __uint_as_float(qu & 0xffff0000u);
                    float klo = __uint_as_float(ku << 16);
                    float khi = __uint_as_float(ku & 0xffff0000u);
                    const int r = r0s + c * 8 + p * 2;
                    float h0 = qdi_s[r]     * klo - kdi_s[r]     * qlo;
                    float h1 = qdi_s[r + 1] * khi - kdi_s[r + 1] * qhi;
                    pk[p] = (uint)f2bf(h0) | ((uint)f2bf(h1) << 16);
                }
                uint4 w; w.x = pk[0]; w.y = pk[1]; w.z = pk[2]; w.w = pk[3];
                *(uint4*)&h_s[jj][r0s + c * 8] = w;
            }
        }
        __syncthreads();

        // ---- per 16-j subtile: hoisted loads, split MFMA chains, fused epilogue ----
#pragma unroll 1
        for (int jsub = 0; jsub < 8; ++jsub) {
            short8 hf[4];
#pragma unroll
            for (int ks = 0; ks < 4; ++ks)
                hf[ks] = *(const short8*)&h_s[jsub * 16 + ln][ks * 32 + quad * 8];
            const int j = jt0 + jsub * 16 + ln;
            const float al = alpha_s[j];
            const size_t trow_ = (size_t)(b * Nn + j) * Dn;
            float4 tjv[4];
#pragma unroll
            for (int dt = 0; dt < 4; ++dt)
                tjv[dt] = *(const float4*)&t[trow_ + wd0 + dt * 16 + quad * 4];

            f32x4 aA[4], aB[4];
#pragma unroll
            for (int dt = 0; dt < 4; ++dt) {
                f32x4 x = {0.f, 0.f, 0.f, 0.f}, y = {0.f, 0.f, 0.f, 0.f};
                x = __builtin_amdgcn_mfma_f32_16x16x32_bf16(vf[dt][0], hf[0], x, 0, 0, 0);
                y = __builtin_amdgcn_mfma_f32_16x16x32_bf16(vf[dt][1], hf[1], y, 0, 0, 0);
                x = __builtin_amdgcn_mfma_f32_16x16x32_bf16(vf[dt][2], hf[2], x, 0, 0, 0);
                y = __builtin_amdgcn_mfma_f32_16x16x32_bf16(vf[dt][3], hf[3], y, 0, 0, 0);
                aA[dt] = x; aB[dt] = y;
            }
#pragma unroll
            for (int dt = 0; dt < 4; ++dt) {
                const float4 tj = tjv[dt];
                float e0 = aA[dt][0] + aB[dt][0];
                float e1 = aA[dt][1] + aB[dt][1];
                float e2 = aA[dt][2] + aB[dt][2];
                float e3 = aA[dt][3] + aB[dt][3];
                float g0 = __builtin_amdgcn_rcpf(1.0f + __builtin_amdgcn_exp2f(e0));
                float g1 = __builtin_amdgcn_rcpf(1.0f + __builtin_amdgcn_exp2f(e1));
                float g2 = __builtin_amdgcn_rcpf(1.0f + __builtin_amdgcn_exp2f(e2));
                float g3 = __builtin_amdgcn_rcpf(1.0f + __builtin_amdgcn_exp2f(e3));
                outac[dt].x += al * g0 * (tiv[dt].x - tj.x);
                outac[dt].y += al * g1 * (tiv[dt].y - tj.y);
                outac[dt].z += al * g2 * (tiv[dt].z - tj.z);
                outac[dt].w += al * g3 * (tiv[dt].w - tj.w);
            }
        }
    }

    // ---- reduce over the 16 j-lanes, write 64 d per wave ----
#pragma unroll
    for (int dt = 0; dt < 4; ++dt) {
        float4 v = outac[dt];
#pragma unroll
        for (int mask = 1; mask < 16; mask <<= 1) {
            v.x += __shfl_xor(v.x, mask);
            v.y += __shfl_xor(v.y, mask);
            v.z += __shfl_xor(v.z, mask);
            v.w += __shfl_xor(v.w, mask);
        }
        if (ln == 0) {
            float4 o;
            o.x = tiv[dt].x - v.x;
            o.y = tiv[dt].y - v.y;
            o.z = tiv[dt].z - v.z;
            o.w = tiv[dt].w - v.w;
            *(float4*)&out[(size_t)bi * Dn + wd0 + dt * 16 + quad * 4] = o;
        }
    }
}

extern "C" void kernel_launch(void* const* d_in, const int* in_sizes, int n_in,
                              void* d_out, int out_size, void* d_ws, size_t ws_size,
                              hipStream_t stream) {
    const float* t   = (const float*)d_in[0];
    const float* Qd  = (const float*)d_in[1];
    const float* Kd  = (const float*)d_in[2];
    const float* Vd  = (const float*)d_in[3];
    const float* Qs  = (const float*)d_in[4];
    const float* Ks  = (const float*)d_in[5];
    const float* a_l = (const float*)d_in[6];
    const float* b_l = (const float*)d_in[7];
    float* out = (float*)d_out;
    float* ws  = (float*)d_ws;

    float* q     = ws;                          // 768*64
    float* k     = q + BNn * Sn;                // 768*64
    float* ssym  = k + BNn * Sn;                // 768*384
    float* m     = ssym + (size_t)BNn * Nn;     // 768
    float* stats = m + BNn;                     // 8
    ushort* qdb  = (ushort*)(stats + 8);        // 768*128 bf16
    ushort* kdb  = qdb + (size_t)BNn * Rn;      // 768*128 bf16
    ushort* VdT  = kdb + (size_t)BNn * Rn;      // 256*128 bf16 (pre-scaled by -log2e)

    hipLaunchKernelGGL(prep_kernel, dim3(320), dim3(256), 0, stream,
                       t, Qd, Kd, Vd, Qs, Ks, q, k, qdb, kdb, VdT, stats);
    hipLaunchKernelGGL(ssym_kernel, dim3(Nn / 16, Nn / 16, Bn), dim3(256), 0, stream,
                       q, k, ssym, stats);
    hipLaunchKernelGGL(m_kernel, dim3(BNn), dim3(256), 0, stream, ssym, stats, a_l, b_l, m);
    hipLaunchKernelGGL(pair_kernel, dim3(BNn), dim3(256), 0, stream,
                       t, ssym, m, stats, a_l, b_l, qdb, kdb, VdT, out);
}